// Round 2
// baseline (202.774 us; speedup 1.0000x reference)
//
#include <hip/hip_runtime.h>

// B=8, C=256, H=W=48 -> N=2304, k=4 -> CK=64
#define BATCH 8
#define CIN   256
#define NPIX  2304
#define CKD   64
#define NIT   (NPIX / 16)  // 144 16-pixel tiles
#define NIC   (NPIX / 32)  // 72 32-i chunks
#define NJB   (NPIX / 64)  // 36 64-j blocks

typedef _Float16 f16;
typedef __attribute__((ext_vector_type(4))) _Float16 f16x4;
typedef __attribute__((ext_vector_type(8))) _Float16 f16x8;
typedef __attribute__((ext_vector_type(4))) float    f32x4;

// Blocked layouts (tile = 512 f16 = 1KB, lane ln owns bytes ln*8..ln*8+15):
//   q_blk[b][IT][ks][512]  A-frag tiles: pix = IT*16 + (ln&15), ck = ks*32+(ln>>4)*8..
//   k_blk[b][JT][ks][512]  B-frag tiles, same internal structure
//   u_blk[b][CT][ic][512]  A-frag tiles: c = CT*16+(ln&15), i = ic*32+(ln>>4)*8..

// ---------------------------------------------------------------------------
// Cast all conv weights fp32 -> f16. Wqk = [qw (64x256); kw (64x256)].
// ---------------------------------------------------------------------------
__global__ __launch_bounds__(256) void cast_w(
    const float* __restrict__ qw, const float* __restrict__ kw,
    const float* __restrict__ vw, const float* __restrict__ gw,
    f16* __restrict__ Wqk, f16* __restrict__ Wv, f16* __restrict__ Wg)
{
    int idx = (blockIdx.x * 256 + threadIdx.x) * 4;
    const float* src;
    f16* dst;
    if (idx < 16384)      { src = qw + idx;           dst = Wqk + idx; }
    else if (idx < 32768) { src = kw + (idx - 16384); dst = Wqk + idx; }
    else if (idx < 98304) { src = vw + (idx - 32768); dst = Wv + (idx - 32768); }
    else                  { src = gw + (idx - 98304); dst = Wg + (idx - 98304); }
    float4 v = *(const float4*)src;
    f16x4 h = { (f16)v.x, (f16)v.y, (f16)v.z, (f16)v.w };
    *(f16x4*)dst = h;
}

// ---------------------------------------------------------------------------
// x[b][c][n] fp32 -> xT[b][n][c] f16 (LDS transpose). Tile 64c x 64n.
// ---------------------------------------------------------------------------
__global__ __launch_bounds__(256) void cast_xT(
    const float* __restrict__ x, f16* __restrict__ xT)
{
    __shared__ float s[64][65];
    const int t = threadIdx.x;
    const int n0 = blockIdx.x * 64, c0 = blockIdx.y * 64, b = blockIdx.z;
    const float* xb = x + ((size_t)b * CIN + c0) * NPIX + n0;

    const int cl = t >> 4, ng = (t & 15) * 4;
    #pragma unroll
    for (int p = 0; p < 4; ++p) {
        float4 v = *(const float4*)(xb + (size_t)(cl + 16 * p) * NPIX + ng);
        s[cl + 16 * p][ng + 0] = v.x;
        s[cl + 16 * p][ng + 1] = v.y;
        s[cl + 16 * p][ng + 2] = v.z;
        s[cl + 16 * p][ng + 3] = v.w;
    }
    __syncthreads();
    const int nl = t >> 2, cs = (t & 3) * 16;
    f16 h[16];
    #pragma unroll
    for (int j = 0; j < 16; ++j) h[j] = (f16)s[cs + j][nl];
    f16* gp = &xT[((size_t)b * NPIX + n0 + nl) * CIN + c0 + cs];
    *(f16x8*)gp       = *(f16x8*)&h[0];
    *(f16x8*)(gp + 8) = *(f16x8*)&h[8];
}

// ---------------------------------------------------------------------------
// q & k conv via MFMA; outputs q_blk / k_blk (frag-blocked) via LDS repack.
// grid (N/32, B), block 256.
// ---------------------------------------------------------------------------
__global__ __launch_bounds__(256) void qk_conv_mfma(
    const f16* __restrict__ xT, const f16* __restrict__ Wqk,
    const float* __restrict__ qbias, const float* __restrict__ kbias,
    f16* __restrict__ q_blk, f16* __restrict__ k_blk)
{
    __shared__ __align__(16) f16 us[32 * 136];   // [n_local][o], stride 272B
    const int t = threadIdx.x, w = t >> 6, lane = t & 63;
    const int quad = lane >> 4, l16 = lane & 15;
    const int wm = w & 1, wn = w >> 1;
    const int n0 = blockIdx.x * 32, b = blockIdx.y;

    const f16* bp = xT + ((size_t)b * NPIX + n0 + 16 * wn + l16) * CIN;
    const f16* ap = Wqk + (size_t)(64 * wm + l16) * CIN;

    f32x4 acc[4];
    #pragma unroll
    for (int mt = 0; mt < 4; ++mt) acc[mt] = (f32x4){0.f, 0.f, 0.f, 0.f};

    #pragma unroll
    for (int kk = 0; kk < CIN; kk += 32) {
        f16x8 bf = *(const f16x8*)(bp + kk + quad * 8);
        #pragma unroll
        for (int mt = 0; mt < 4; ++mt) {
            f16x8 af = *(const f16x8*)(ap + (size_t)mt * 16 * CIN + kk + quad * 8);
            acc[mt] = __builtin_amdgcn_mfma_f32_16x16x32_f16(af, bf, acc[mt], 0, 0, 0);
        }
    }
    const float* bias = wm ? kbias - 64 : qbias;   // o-indexed
    #pragma unroll
    for (int mt = 0; mt < 4; ++mt) {
        int ob = 64 * wm + 16 * mt + quad * 4;
        #pragma unroll
        for (int r = 0; r < 4; ++r)
            us[(16 * wn + l16) * 136 + ob + r] = (f16)(acc[mt][r] + bias[ob + r]);
    }
    __syncthreads();
    // blocked stores: thread t -> (ks = t>>7, nt = (t>>6)&1, ln = t&63)
    {
        int ks2 = t >> 7, nt = (t >> 6) & 1, ln = t & 63;
        const f16* usr = &us[(nt * 16 + (ln & 15)) * 136 + ks2 * 32 + (ln >> 4) * 8];
        size_t base = (((size_t)b * NIT + (n0 >> 4) + nt) * 2 + ks2) * 512 + ln * 8;
        *(f16x8*)&q_blk[base] = *(const f16x8*)(usr);
        *(f16x8*)&k_blk[base] = *(const f16x8*)(usr + 64);
    }
}

// ---------------------------------------------------------------------------
// S-only energy pass: partial row sums of f16(exp(q_i.k_j)) per 64-j block.
// Blocked (contiguous) frag loads; no Et store. grid (N/64 j, N/128 i, B).
// ---------------------------------------------------------------------------
#define ESL 136
__global__ __launch_bounds__(256) void energy_S(
    const f16* __restrict__ q_blk, const f16* __restrict__ k_blk,
    float* __restrict__ Pred)
{
    __shared__ __align__(16) f16 es[64 * ESL];
    __shared__ float red2[2][128];
    const int t    = threadIdx.x;
    const int w    = t >> 6, lane = t & 63;
    const int quad = lane >> 4, l16 = lane & 15;
    const int j0 = blockIdx.x * 64, i0 = blockIdx.y * 128, b = blockIdx.z;
    const size_t ln8 = (size_t)lane * 8;
    const f16* qb = q_blk + (size_t)b * NIT * 2 * 512 + ln8;

    f32x4 acc[8];
    #pragma unroll
    for (int mt = 0; mt < 8; ++mt) acc[mt] = (f32x4){0.f, 0.f, 0.f, 0.f};

    #pragma unroll
    for (int ks = 0; ks < 2; ++ks) {
        f16x8 bf = *(const f16x8*)(k_blk +
            (((size_t)b * NIT + (j0 >> 4) + w) * 2 + ks) * 512 + ln8);
        #pragma unroll
        for (int mt = 0; mt < 8; ++mt) {
            f16x8 af = *(const f16x8*)(qb + ((size_t)((i0 >> 4) + mt) * 2 + ks) * 512);
            acc[mt] = __builtin_amdgcn_mfma_f32_16x16x32_f16(af, bf, acc[mt], 0, 0, 0);
        }
    }

    // exp -> LDS es[j][i] (lane: j = 16w+l16, i = 16mt+quad*4+r)
    #pragma unroll
    for (int mt = 0; mt < 8; ++mt) {
        f16x4 h = { (f16)__expf(acc[mt][0]), (f16)__expf(acc[mt][1]),
                    (f16)__expf(acc[mt][2]), (f16)__expf(acc[mt][3]) };
        *(f16x4*)&es[(16 * w + l16) * ESL + 16 * mt + quad * 4] = h;
    }
    __syncthreads();
    {
        int i = t & 127, jq = t >> 7;
        float s = 0.f;
        #pragma unroll
        for (int jj = 0; jj < 32; ++jj)
            s += (float)es[(jq * 32 + jj) * ESL + i];
        red2[jq][i] = s;
    }
    __syncthreads();
    if (t < 128)
        Pred[((size_t)blockIdx.x * BATCH + b) * NPIX + i0 + t] =
            red2[0][t] + red2[1][t];
}

// ---------------------------------------------------------------------------
// S[b,i] = sum over 36 j-block partials (coalesced). grid BN/256.
// ---------------------------------------------------------------------------
__global__ __launch_bounds__(256) void reduce_S(
    const float* __restrict__ Pred, float* __restrict__ S)
{
    const size_t BN = (size_t)BATCH * NPIX;
    size_t idx = (size_t)blockIdx.x * 256 + threadIdx.x;
    float s = 0.f;
    #pragma unroll
    for (int jb = 0; jb < NJB; ++jb)
        s += Pred[(size_t)jb * BN + idx];
    S[idx] = s;
}

// ---------------------------------------------------------------------------
// v conv via MFMA, fused bias + 1/S scale; output u_blk (A-frag-blocked).
// Tile 128(c) x 64(i), BK=32. grid (N/64, C/128, B), block 256.
// ---------------------------------------------------------------------------
__global__ __launch_bounds__(256) void v_conv_mfma(
    const f16* __restrict__ xT, const f16* __restrict__ Wv,
    const float* __restrict__ vbias, const float* __restrict__ S,
    f16* __restrict__ u_blk)
{
    __shared__ __align__(16) f16 smem[9216];   // As 128*40 | Bs 64*40; reused as us 128*72
    f16* As = smem;
    f16* Bs = smem + 128 * 40;
    f16* us = smem;
    const int t = threadIdx.x, w = t >> 6, lane = t & 63;
    const int quad = lane >> 4, l16 = lane & 15;
    const int wm = w & 1, wn = w >> 1;
    const int i0 = blockIdx.x * 64, c0 = blockIdx.y * 128, b = blockIdx.z;
    const int sub = t >> 2, le = t & 3;
    const f16* srcA = Wv + (size_t)(c0 + sub) * CIN + le * 8;
    const f16* srcB = xT + ((size_t)b * NPIX + i0 + sub) * CIN + le * 8;
    const int ldsw = sub * 40 + le * 8;

    f32x4 acc[4][2];
    #pragma unroll
    for (int mt = 0; mt < 4; ++mt)
        #pragma unroll
        for (int nt = 0; nt < 2; ++nt)
            acc[mt][nt] = (f32x4){0.f, 0.f, 0.f, 0.f};

    for (int kk = 0; kk < CIN; kk += 32) {
        f16x8 ta0 = *(const f16x8*)(srcA + kk);
        f16x8 ta1 = *(const f16x8*)(srcA + (size_t)64 * CIN + kk);
        f16x8 tb0 = *(const f16x8*)(srcB + kk);
        __syncthreads();
        *(f16x8*)&As[ldsw]           = ta0;
        *(f16x8*)&As[64 * 40 + ldsw] = ta1;
        *(f16x8*)&Bs[ldsw]           = tb0;
        __syncthreads();
        f16x8 af[4], bf[2];
        #pragma unroll
        for (int mt = 0; mt < 4; ++mt)
            af[mt] = *(const f16x8*)&As[(64 * wm + 16 * mt + l16) * 40 + quad * 8];
        #pragma unroll
        for (int nt = 0; nt < 2; ++nt)
            bf[nt] = *(const f16x8*)&Bs[(32 * wn + 16 * nt + l16) * 40 + quad * 8];
        #pragma unroll
        for (int mt = 0; mt < 4; ++mt)
            #pragma unroll
            for (int nt = 0; nt < 2; ++nt)
                acc[mt][nt] = __builtin_amdgcn_mfma_f32_16x16x32_f16(
                    af[mt], bf[nt], acc[mt][nt], 0, 0, 0);
    }

    __syncthreads();   // As/Bs dead; reuse as us[c][i] (stride 72)
    #pragma unroll
    for (int nt = 0; nt < 2; ++nt) {
        int i = 32 * wn + 16 * nt + l16;
        float is = 1.0f / S[(size_t)b * NPIX + i0 + i];
        #pragma unroll
        for (int mt = 0; mt < 4; ++mt)
            #pragma unroll
            for (int r = 0; r < 4; ++r) {
                int c = 64 * wm + 16 * mt + quad * 4 + r;
                us[c * 72 + i] = (f16)((acc[mt][nt][r] + vbias[c0 + c]) * is);
            }
    }
    __syncthreads();
    #pragma unroll
    for (int p = 0; p < 4; ++p) {
        int g  = t + 256 * p;
        int ct = g >> 7, ic = (g >> 6) & 1, ln = g & 63;
        f16x8 v = *(const f16x8*)&us[(ct * 16 + (ln & 15)) * 72 + ic * 32 + (ln >> 4) * 8];
        *(f16x8*)&u_blk[(((size_t)b * 16 + (c0 >> 4) + ct) * NIC + (i0 >> 5) + ic) * 512 + ln * 8] = v;
    }
}

// ---------------------------------------------------------------------------
// FUSED bmm: o1T[b,j,c] = sum_i u[c,i] * f16(exp(q_i.k_j))
// Block 64j x 256c, 8 waves (512 thr). Flat grid 288, b = bid&7 so all
// blocks of batch b land on XCD b (HW round-robin) -> u_blk[b] (1.18MB) +
// q_blk[b] (0.29MB) stay resident in that XCD's 4MB L2.
// Per 64-i chunk:
//  stage1 (4 MFMA/wave): wave w = (iw=w>>1, jh=w&1) computes E tiles
//    (it=iw, jt=jh) and (it=iw, jt=jh+2) -> exp -> es B-frag blocked tiles
//  stage2 (16 MFMA/wave): acc(32c x 64j) += u A-frags x es B-frags
// es double-buffered -> single __syncthreads per chunk.
// grid 288, block 512, 2 blocks/CU.
// ---------------------------------------------------------------------------
__global__ __launch_bounds__(512, 4) void fused_bmm(
    const f16* __restrict__ q_blk, const f16* __restrict__ k_blk,
    const f16* __restrict__ u_blk, f16* __restrict__ o1T)
{
    // es[buf][jt*2+isub][512]: B-frag tiles (16j x 32i) of f16(exp(E))
    __shared__ __align__(16) f16 es[2][8][512];
    const int t = threadIdx.x, w = t >> 6, lane = t & 63;
    const int quad = lane >> 4, l16 = lane & 15;
    const int bid = blockIdx.x;
    const int b  = bid & 7;            // XCD-batch affinity
    const int j0 = (bid >> 3) * 64;
    const size_t ln8 = (size_t)lane * 8;

    const f16* qb = q_blk + (size_t)b * NIT * 2 * 512 + ln8;
    const f16* ub = u_blk + (size_t)b * 16 * NIC * 512 + ln8;

    const int iw = w >> 1;       // stage-1 i-16-tile index (0..3) in 64-i chunk
    const int jh = w & 1;        // stage-1 j-tiles: jh and jh+2

    // k-frags for this wave's two stage-1 j-tiles, resident for whole kernel
    f16x8 kf[2][2];
    #pragma unroll
    for (int jj = 0; jj < 2; ++jj)
        #pragma unroll
        for (int ks = 0; ks < 2; ++ks)
            kf[jj][ks] = *(const f16x8*)(k_blk +
                (((size_t)b * NIT + (j0 >> 4) + jh + 2 * jj) * 2 + ks) * 512 + ln8);

    const int CT0 = w * 2;       // this wave's two u c-tiles (c = 32w..32w+31)
    // stage-1 write: intra-tile offset (blocked B-frag layout)
    //   elem (j,i): off = (i>>3)*128 + j*8 + (i&7); lane holds j=l16,
    //   i = (iw&1)*16 + quad*4 + r  ->  4 consecutive f16
    const int woff = ((iw & 1) * 2 + (quad >> 1)) * 128 + l16 * 8 + (quad & 1) * 4;
    const int et0 = jh * 2 + (iw >> 1);        // es tile for jt=jh
    const int et1 = (jh + 2) * 2 + (iw >> 1);  // es tile for jt=jh+2

    f32x4 acc[2][4];   // [c-tile mt][j-tile jt]
    #pragma unroll
    for (int mt = 0; mt < 2; ++mt)
        #pragma unroll
        for (int jt = 0; jt < 4; ++jt)
            acc[mt][jt] = (f32x4){0.f, 0.f, 0.f, 0.f};

    for (int ic = 0; ic < NPIX / 64; ++ic) {
        const int cur = ic & 1;
        // ---- stage 1: two 16i x 16j E tiles (same i-tile, j-tiles jh, jh+2)
        f32x4 e0 = (f32x4){0.f, 0.f, 0.f, 0.f};
        f32x4 e1 = (f32x4){0.f, 0.f, 0.f, 0.f};
        #pragma unroll
        for (int ks = 0; ks < 2; ++ks) {
            f16x8 af = *(const f16x8*)(qb + ((size_t)(ic * 4 + iw) * 2 + ks) * 512);
            e0 = __builtin_amdgcn_mfma_f32_16x16x32_f16(af, kf[0][ks], e0, 0, 0, 0);
            e1 = __builtin_amdgcn_mfma_f32_16x16x32_f16(af, kf[1][ks], e1, 0, 0, 0);
        }
        f16x4 h0 = { (f16)__expf(e0[0]), (f16)__expf(e0[1]),
                     (f16)__expf(e0[2]), (f16)__expf(e0[3]) };
        f16x4 h1 = { (f16)__expf(e1[0]), (f16)__expf(e1[1]),
                     (f16)__expf(e1[2]), (f16)__expf(e1[3]) };
        *(f16x4*)&es[cur][et0][woff] = h0;
        *(f16x4*)&es[cur][et1][woff] = h1;
        __syncthreads();
        // ---- stage 2: 32c x 64j x 64i
        #pragma unroll
        for (int isub = 0; isub < 2; ++isub) {
            f16x8 af0 = *(const f16x8*)(ub + ((size_t)(CT0 + 0) * NIC + ic * 2 + isub) * 512);
            f16x8 af1 = *(const f16x8*)(ub + ((size_t)(CT0 + 1) * NIC + ic * 2 + isub) * 512);
            #pragma unroll
            for (int jt = 0; jt < 4; ++jt) {
                f16x8 bf = *(const f16x8*)&es[cur][jt * 2 + isub][ln8];
                acc[0][jt] = __builtin_amdgcn_mfma_f32_16x16x32_f16(af0, bf, acc[0][jt], 0, 0, 0);
                acc[1][jt] = __builtin_amdgcn_mfma_f32_16x16x32_f16(af1, bf, acc[1][jt], 0, 0, 0);
            }
        }
    }

    #pragma unroll
    for (int mt = 0; mt < 2; ++mt) {
        int cb = 32 * w + 16 * mt + quad * 4;
        #pragma unroll
        for (int jt = 0; jt < 4; ++jt) {
            int j = j0 + 16 * jt + l16;
            f16x4 h2 = { (f16)acc[mt][jt][0], (f16)acc[mt][jt][1],
                         (f16)acc[mt][jt][2], (f16)acc[mt][jt][3] };
            *(f16x4*)&o1T[((size_t)b * NPIX + j) * CIN + cb] = h2;
        }
    }
}

// ---------------------------------------------------------------------------
// Gamma conv via MFMA: out[b,o,j] = sum_c Wg[o,c]*o1[c,j] + gb[o], fp32 out.
// Tile 128(o) x 64(j), BK=32. grid (N/64, C/128, B), block 256.
// ---------------------------------------------------------------------------
__global__ __launch_bounds__(256) void gamma_conv_mfma(
    const f16* __restrict__ o1T, const f16* __restrict__ Wg,
    const float* __restrict__ gbias, float* __restrict__ out)
{
    __shared__ __align__(16) f16 As[128 * 40];
    __shared__ __align__(16) f16 Bs[64 * 40];
    const int t = threadIdx.x, w = t >> 6, lane = t & 63;
    const int quad = lane >> 4, l16 = lane & 15;
    const int wm = w & 1, wn = w >> 1;
    const int j0 = blockIdx.x * 64, o0 = blockIdx.y * 128, b = blockIdx.z;
    const int sub = t >> 2, le = t & 3;
    const f16* srcA = Wg + (size_t)(o0 + sub) * CIN + le * 8;
    const f16* srcB = o1T + ((size_t)b * NPIX + j0 + sub) * CIN + le * 8;
    const int ldsw = sub * 40 + le * 8;

    f32x4 acc[4][2];
    #pragma unroll
    for (int mt = 0; mt < 4; ++mt)
        #pragma unroll
        for (int nt = 0; nt < 2; ++nt)
            acc[mt][nt] = (f32x4){0.f, 0.f, 0.f, 0.f};

    for (int kk = 0; kk < CIN; kk += 32) {
        f16x8 ta0 = *(const f16x8*)(srcA + kk);
        f16x8 ta1 = *(const f16x8*)(srcA + (size_t)64 * CIN + kk);
        f16x8 tb0 = *(const f16x8*)(srcB + kk);
        __syncthreads();
        *(f16x8*)&As[ldsw]           = ta0;
        *(f16x8*)&As[64 * 40 + ldsw] = ta1;
        *(f16x8*)&Bs[ldsw]           = tb0;
        __syncthreads();
        f16x8 af[4], bf[2];
        #pragma unroll
        for (int mt = 0; mt < 4; ++mt)
            af[mt] = *(const f16x8*)&As[(64 * wm + 16 * mt + l16) * 40 + quad * 8];
        #pragma unroll
        for (int nt = 0; nt < 2; ++nt)
            bf[nt] = *(const f16x8*)&Bs[(32 * wn + 16 * nt + l16) * 40 + quad * 8];
        #pragma unroll
        for (int mt = 0; mt < 4; ++mt)
            #pragma unroll
            for (int nt = 0; nt < 2; ++nt)
                acc[mt][nt] = __builtin_amdgcn_mfma_f32_16x16x32_f16(
                    af[mt], bf[nt], acc[mt][nt], 0, 0, 0);
    }

    #pragma unroll
    for (int mt = 0; mt < 4; ++mt)
        #pragma unroll
        for (int r = 0; r < 4; ++r) {
            int o = o0 + 64 * wm + 16 * mt + quad * 4 + r;
            float bv = gbias[o];
            #pragma unroll
            for (int nt = 0; nt < 2; ++nt) {
                int j = j0 + 32 * wn + 16 * nt + l16;
                out[((size_t)b * CIN + o) * NPIX + j] = acc[mt][nt][r] + bv;
            }
        }
}

// ---------------------------------------------------------------------------
extern "C" void kernel_launch(void* const* d_in, const int* in_sizes, int n_in,
                              void* d_out, int out_size, void* d_ws, size_t ws_size,
                              hipStream_t stream) {
    const float* x   = (const float*)d_in[0];
    const float* qw  = (const float*)d_in[1];
    const float* qbv = (const float*)d_in[2];
    const float* kw  = (const float*)d_in[3];
    const float* kbv = (const float*)d_in[4];
    const float* vw  = (const float*)d_in[5];
    const float* vbv = (const float*)d_in[6];
    const float* gw  = (const float*)d_in[7];
    const float* gbv = (const float*)d_in[8];
    float* out = (float*)d_out;

    const size_t BCN  = (size_t)BATCH * CIN * NPIX;   // 4,718,592
    const size_t BN   = (size_t)BATCH * NPIX;         // 18,432
    const size_t BNCK = (size_t)BATCH * NPIX * CKD;   // 1,179,648

    // ws layout (~36 MB)
    f16* q_blk = (f16*)d_ws;          // 2.36 MB
    f16* k_blk = q_blk + BNCK;        // 2.36 MB
    f16* u_blk = k_blk + BNCK;        // 9.44 MB
    f16* xT    = u_blk + BCN;         // 9.44 MB
    f16* o1T   = xT + BCN;            // 9.44 MB
    f16* Wqk   = o1T + BCN;
    f16* Wv    = Wqk + 128 * 256;
    f16* Wg    = Wv + 256 * 256;
    float* S   = (float*)(Wg + 256 * 256);   // 0.07 MB
    float* Pred= S + BN;                      // 2.65 MB

    cast_w<<<160, 256, 0, stream>>>(qw, kw, vw, gw, Wqk, Wv, Wg);
    cast_xT<<<dim3(NPIX / 64, CIN / 64, BATCH), 256, 0, stream>>>(x, xT);
    qk_conv_mfma<<<dim3(NPIX / 32, BATCH), 256, 0, stream>>>(xT, Wqk, qbv, kbv, q_blk, k_blk);
    energy_S<<<dim3(NPIX / 64, NPIX / 128, BATCH), 256, 0, stream>>>(q_blk, k_blk, Pred);
    reduce_S<<<(int)(BN / 256), 256, 0, stream>>>(Pred, S);
    v_conv_mfma<<<dim3(NPIX / 64, CIN / 128, BATCH), 256, 0, stream>>>(xT, Wv, vbv, S, u_blk);
    fused_bmm<<<NJB * BATCH, 512, 0, stream>>>(q_blk, k_blk, u_blk, o1T);
    gamma_conv_mfma<<<dim3(NPIX / 64, CIN / 128, BATCH), 256, 0, stream>>>(o1T, Wg, gbv, out);
}

// Round 3
// 191.974 us; speedup vs baseline: 1.0563x; 1.0563x over previous
//
#include <hip/hip_runtime.h>

// B=8, C=256, H=W=48 -> N=2304, k=4 -> CK=64
#define BATCH 8
#define CIN   256
#define NPIX  2304
#define CKD   64
#define NIT   (NPIX / 16)  // 144 16-pixel tiles
#define NIC   (NPIX / 32)  // 72 32-i chunks
#define NJB   (NPIX / 64)  // 36 64-j blocks
#define NCH   (NPIX / 64)  // 36 64-i chunks

typedef _Float16 f16;
typedef __attribute__((ext_vector_type(4))) _Float16 f16x4;
typedef __attribute__((ext_vector_type(8))) _Float16 f16x8;
typedef __attribute__((ext_vector_type(4))) float    f32x4;

// Blocked layouts (tile = 512 f16 = 1KB, lane ln owns bytes ln*8..ln*8+15):
//   q_blk[b][IT][ks][512]  A-frag tiles: pix = IT*16 + (ln&15), ck = ks*32+(ln>>4)*8..
//   k_blk[b][JT][ks][512]  B-frag tiles, same internal structure
//   u_blk[b][CT][ic][512]  A-frag tiles: c = CT*16+(ln&15), i = ic*32+(ln>>4)*8..

// ---------------------------------------------------------------------------
// Cast all conv weights fp32 -> f16. Wqk = [qw (64x256); kw (64x256)].
// ---------------------------------------------------------------------------
__global__ __launch_bounds__(256) void cast_w(
    const float* __restrict__ qw, const float* __restrict__ kw,
    const float* __restrict__ vw, const float* __restrict__ gw,
    f16* __restrict__ Wqk, f16* __restrict__ Wv, f16* __restrict__ Wg)
{
    int idx = (blockIdx.x * 256 + threadIdx.x) * 4;
    const float* src;
    f16* dst;
    if (idx < 16384)      { src = qw + idx;           dst = Wqk + idx; }
    else if (idx < 32768) { src = kw + (idx - 16384); dst = Wqk + idx; }
    else if (idx < 98304) { src = vw + (idx - 32768); dst = Wv + (idx - 32768); }
    else                  { src = gw + (idx - 98304); dst = Wg + (idx - 98304); }
    float4 v = *(const float4*)src;
    f16x4 h = { (f16)v.x, (f16)v.y, (f16)v.z, (f16)v.w };
    *(f16x4*)dst = h;
}

// ---------------------------------------------------------------------------
// x[b][c][n] fp32 -> xT[b][n][c] f16 (LDS transpose). Tile 64c x 64n.
// ---------------------------------------------------------------------------
__global__ __launch_bounds__(256) void cast_xT(
    const float* __restrict__ x, f16* __restrict__ xT)
{
    __shared__ float s[64][65];
    const int t = threadIdx.x;
    const int n0 = blockIdx.x * 64, c0 = blockIdx.y * 64, b = blockIdx.z;
    const float* xb = x + ((size_t)b * CIN + c0) * NPIX + n0;

    const int cl = t >> 4, ng = (t & 15) * 4;
    #pragma unroll
    for (int p = 0; p < 4; ++p) {
        float4 v = *(const float4*)(xb + (size_t)(cl + 16 * p) * NPIX + ng);
        s[cl + 16 * p][ng + 0] = v.x;
        s[cl + 16 * p][ng + 1] = v.y;
        s[cl + 16 * p][ng + 2] = v.z;
        s[cl + 16 * p][ng + 3] = v.w;
    }
    __syncthreads();
    const int nl = t >> 2, cs = (t & 3) * 16;
    f16 h[16];
    #pragma unroll
    for (int j = 0; j < 16; ++j) h[j] = (f16)s[cs + j][nl];
    f16* gp = &xT[((size_t)b * NPIX + n0 + nl) * CIN + c0 + cs];
    *(f16x8*)gp       = *(f16x8*)&h[0];
    *(f16x8*)(gp + 8) = *(f16x8*)&h[8];
}

// ---------------------------------------------------------------------------
// q & k conv via MFMA; outputs q_blk / k_blk (frag-blocked) via LDS repack.
// grid (N/32, B), block 256.
// ---------------------------------------------------------------------------
__global__ __launch_bounds__(256) void qk_conv_mfma(
    const f16* __restrict__ xT, const f16* __restrict__ Wqk,
    const float* __restrict__ qbias, const float* __restrict__ kbias,
    f16* __restrict__ q_blk, f16* __restrict__ k_blk)
{
    __shared__ __align__(16) f16 us[32 * 136];   // [n_local][o], stride 272B
    const int t = threadIdx.x, w = t >> 6, lane = t & 63;
    const int quad = lane >> 4, l16 = lane & 15;
    const int wm = w & 1, wn = w >> 1;
    const int n0 = blockIdx.x * 32, b = blockIdx.y;

    const f16* bp = xT + ((size_t)b * NPIX + n0 + 16 * wn + l16) * CIN;
    const f16* ap = Wqk + (size_t)(64 * wm + l16) * CIN;

    f32x4 acc[4];
    #pragma unroll
    for (int mt = 0; mt < 4; ++mt) acc[mt] = (f32x4){0.f, 0.f, 0.f, 0.f};

    #pragma unroll
    for (int kk = 0; kk < CIN; kk += 32) {
        f16x8 bf = *(const f16x8*)(bp + kk + quad * 8);
        #pragma unroll
        for (int mt = 0; mt < 4; ++mt) {
            f16x8 af = *(const f16x8*)(ap + (size_t)mt * 16 * CIN + kk + quad * 8);
            acc[mt] = __builtin_amdgcn_mfma_f32_16x16x32_f16(af, bf, acc[mt], 0, 0, 0);
        }
    }
    const float* bias = wm ? kbias - 64 : qbias;   // o-indexed
    #pragma unroll
    for (int mt = 0; mt < 4; ++mt) {
        int ob = 64 * wm + 16 * mt + quad * 4;
        #pragma unroll
        for (int r = 0; r < 4; ++r)
            us[(16 * wn + l16) * 136 + ob + r] = (f16)(acc[mt][r] + bias[ob + r]);
    }
    __syncthreads();
    // blocked stores: thread t -> (ks = t>>7, nt = (t>>6)&1, ln = t&63)
    {
        int ks2 = t >> 7, nt = (t >> 6) & 1, ln = t & 63;
        const f16* usr = &us[(nt * 16 + (ln & 15)) * 136 + ks2 * 32 + (ln >> 4) * 8];
        size_t base = (((size_t)b * NIT + (n0 >> 4) + nt) * 2 + ks2) * 512 + ln * 8;
        *(f16x8*)&q_blk[base] = *(const f16x8*)(usr);
        *(f16x8*)&k_blk[base] = *(const f16x8*)(usr + 64);
    }
}

// ---------------------------------------------------------------------------
// S-only energy pass: partial row sums of f16(exp(q_i.k_j)) per 64-j block.
// Blocked (contiguous) frag loads; no Et store. grid (N/64 j, N/128 i, B).
// ---------------------------------------------------------------------------
#define ESL 136
__global__ __launch_bounds__(256) void energy_S(
    const f16* __restrict__ q_blk, const f16* __restrict__ k_blk,
    float* __restrict__ Pred)
{
    __shared__ __align__(16) f16 es[64 * ESL];
    __shared__ float red2[2][128];
    const int t    = threadIdx.x;
    const int w    = t >> 6, lane = t & 63;
    const int quad = lane >> 4, l16 = lane & 15;
    const int j0 = blockIdx.x * 64, i0 = blockIdx.y * 128, b = blockIdx.z;
    const size_t ln8 = (size_t)lane * 8;
    const f16* qb = q_blk + (size_t)b * NIT * 2 * 512 + ln8;

    f32x4 acc[8];
    #pragma unroll
    for (int mt = 0; mt < 8; ++mt) acc[mt] = (f32x4){0.f, 0.f, 0.f, 0.f};

    #pragma unroll
    for (int ks = 0; ks < 2; ++ks) {
        f16x8 bf = *(const f16x8*)(k_blk +
            (((size_t)b * NIT + (j0 >> 4) + w) * 2 + ks) * 512 + ln8);
        #pragma unroll
        for (int mt = 0; mt < 8; ++mt) {
            f16x8 af = *(const f16x8*)(qb + ((size_t)((i0 >> 4) + mt) * 2 + ks) * 512);
            acc[mt] = __builtin_amdgcn_mfma_f32_16x16x32_f16(af, bf, acc[mt], 0, 0, 0);
        }
    }

    // exp -> LDS es[j][i] (lane: j = 16w+l16, i = 16mt+quad*4+r)
    #pragma unroll
    for (int mt = 0; mt < 8; ++mt) {
        f16x4 h = { (f16)__expf(acc[mt][0]), (f16)__expf(acc[mt][1]),
                    (f16)__expf(acc[mt][2]), (f16)__expf(acc[mt][3]) };
        *(f16x4*)&es[(16 * w + l16) * ESL + 16 * mt + quad * 4] = h;
    }
    __syncthreads();
    {
        int i = t & 127, jq = t >> 7;
        float s = 0.f;
        #pragma unroll
        for (int jj = 0; jj < 32; ++jj)
            s += (float)es[(jq * 32 + jj) * ESL + i];
        red2[jq][i] = s;
    }
    __syncthreads();
    if (t < 128)
        Pred[((size_t)blockIdx.x * BATCH + b) * NPIX + i0 + t] =
            red2[0][t] + red2[1][t];
}

// ---------------------------------------------------------------------------
// S[b,i] = sum over 36 j-block partials (coalesced). grid BN/256.
// ---------------------------------------------------------------------------
__global__ __launch_bounds__(256) void reduce_S(
    const float* __restrict__ Pred, float* __restrict__ S)
{
    const size_t BN = (size_t)BATCH * NPIX;
    size_t idx = (size_t)blockIdx.x * 256 + threadIdx.x;
    float s = 0.f;
    #pragma unroll
    for (int jb = 0; jb < NJB; ++jb)
        s += Pred[(size_t)jb * BN + idx];
    S[idx] = s;
}

// ---------------------------------------------------------------------------
// v conv via MFMA, fused bias + 1/S scale; output u_blk (A-frag-blocked).
// Tile 128(c) x 64(i), BK=32. grid (N/64, C/128, B), block 256.
// ---------------------------------------------------------------------------
__global__ __launch_bounds__(256) void v_conv_mfma(
    const f16* __restrict__ xT, const f16* __restrict__ Wv,
    const float* __restrict__ vbias, const float* __restrict__ S,
    f16* __restrict__ u_blk)
{
    __shared__ __align__(16) f16 smem[9216];   // As 128*40 | Bs 64*40; reused as us 128*72
    f16* As = smem;
    f16* Bs = smem + 128 * 40;
    f16* us = smem;
    const int t = threadIdx.x, w = t >> 6, lane = t & 63;
    const int quad = lane >> 4, l16 = lane & 15;
    const int wm = w & 1, wn = w >> 1;
    const int i0 = blockIdx.x * 64, c0 = blockIdx.y * 128, b = blockIdx.z;
    const int sub = t >> 2, le = t & 3;
    const f16* srcA = Wv + (size_t)(c0 + sub) * CIN + le * 8;
    const f16* srcB = xT + ((size_t)b * NPIX + i0 + sub) * CIN + le * 8;
    const int ldsw = sub * 40 + le * 8;

    f32x4 acc[4][2];
    #pragma unroll
    for (int mt = 0; mt < 4; ++mt)
        #pragma unroll
        for (int nt = 0; nt < 2; ++nt)
            acc[mt][nt] = (f32x4){0.f, 0.f, 0.f, 0.f};

    for (int kk = 0; kk < CIN; kk += 32) {
        f16x8 ta0 = *(const f16x8*)(srcA + kk);
        f16x8 ta1 = *(const f16x8*)(srcA + (size_t)64 * CIN + kk);
        f16x8 tb0 = *(const f16x8*)(srcB + kk);
        __syncthreads();
        *(f16x8*)&As[ldsw]           = ta0;
        *(f16x8*)&As[64 * 40 + ldsw] = ta1;
        *(f16x8*)&Bs[ldsw]           = tb0;
        __syncthreads();
        f16x8 af[4], bf[2];
        #pragma unroll
        for (int mt = 0; mt < 4; ++mt)
            af[mt] = *(const f16x8*)&As[(64 * wm + 16 * mt + l16) * 40 + quad * 8];
        #pragma unroll
        for (int nt = 0; nt < 2; ++nt)
            bf[nt] = *(const f16x8*)&Bs[(32 * wn + 16 * nt + l16) * 40 + quad * 8];
        #pragma unroll
        for (int mt = 0; mt < 4; ++mt)
            #pragma unroll
            for (int nt = 0; nt < 2; ++nt)
                acc[mt][nt] = __builtin_amdgcn_mfma_f32_16x16x32_f16(
                    af[mt], bf[nt], acc[mt][nt], 0, 0, 0);
    }

    __syncthreads();   // As/Bs dead; reuse as us[c][i] (stride 72)
    #pragma unroll
    for (int nt = 0; nt < 2; ++nt) {
        int i = 32 * wn + 16 * nt + l16;
        float is = 1.0f / S[(size_t)b * NPIX + i0 + i];
        #pragma unroll
        for (int mt = 0; mt < 4; ++mt)
            #pragma unroll
            for (int r = 0; r < 4; ++r) {
                int c = 64 * wm + 16 * mt + quad * 4 + r;
                us[c * 72 + i] = (f16)((acc[mt][nt][r] + vbias[c0 + c]) * is);
            }
    }
    __syncthreads();
    #pragma unroll
    for (int p = 0; p < 4; ++p) {
        int g  = t + 256 * p;
        int ct = g >> 7, ic = (g >> 6) & 1, ln = g & 63;
        f16x8 v = *(const f16x8*)&us[(ct * 16 + (ln & 15)) * 72 + ic * 32 + (ln >> 4) * 8];
        *(f16x8*)&u_blk[(((size_t)b * 16 + (c0 >> 4) + ct) * NIC + (i0 >> 5) + ic) * 512 + ln * 8] = v;
    }
}

// ---------------------------------------------------------------------------
// FUSED bmm: o1T[b,j,c] = sum_i u[c,i] * f16(exp(q_i.k_j))
// Block 64j x 256c, 8 waves. XCD-batch affinity (b = bid&7).
// SOFTWARE-PIPELINED: iteration ic overlaps
//   {issue loads U(ic+1), Q(ic+2)} | stage2(ic) 16 MFMA | stage1 E(ic+1)
// with ping-pong register sets; raw s_barrier + lgkmcnt(0) only (no vmcnt
// drain) so global prefetches stay in flight across the barrier.
// grid 288, block 512.
// ---------------------------------------------------------------------------
__global__ __launch_bounds__(512, 4) void fused_bmm(
    const f16* __restrict__ q_blk, const f16* __restrict__ k_blk,
    const f16* __restrict__ u_blk, f16* __restrict__ o1T)
{
    // es[buf][jt*2+isub][512]: B-frag tiles (16j x 32i) of f16(exp(E))
    __shared__ __align__(16) f16 es[2][8][512];
    const int t = threadIdx.x, w = t >> 6, lane = t & 63;
    const int quad = lane >> 4, l16 = lane & 15;
    const int bid = blockIdx.x;
    const int b  = bid & 7;            // XCD-batch affinity
    const int j0 = (bid >> 3) * 64;
    const size_t ln8 = (size_t)lane * 8;

    const f16* qb = q_blk + (size_t)b * NIT * 2 * 512 + ln8;
    const f16* ub = u_blk + (size_t)b * 16 * NIC * 512 + ln8;

    const int iw = w >> 1;       // stage-1 i-16-tile index (0..3) in 64-i chunk
    const int jh = w & 1;        // stage-1 j-tiles: jh and jh+2

    // k-frags for this wave's two stage-1 j-tiles, resident for whole kernel
    f16x8 kf[2][2];
    #pragma unroll
    for (int jj = 0; jj < 2; ++jj)
        #pragma unroll
        for (int ks = 0; ks < 2; ++ks)
            kf[jj][ks] = *(const f16x8*)(k_blk +
                (((size_t)b * NIT + (j0 >> 4) + jh + 2 * jj) * 2 + ks) * 512 + ln8);

    const int CT0 = w * 2;       // this wave's two u c-tiles (c = 32w..32w+31)
    // stage-1 write: intra-tile offset (blocked B-frag layout)
    const int woff = ((iw & 1) * 2 + (quad >> 1)) * 128 + l16 * 8 + (quad & 1) * 4;
    const int et0 = jh * 2 + (iw >> 1);        // es tile for jt=jh
    const int et1 = (jh + 2) * 2 + (iw >> 1);  // es tile for jt=jh+2

    f32x4 acc[2][4];   // [c-tile mt][j-tile jt]
    #pragma unroll
    for (int mt = 0; mt < 2; ++mt)
        #pragma unroll
        for (int jt = 0; jt < 4; ++jt)
            acc[mt][jt] = (f32x4){0.f, 0.f, 0.f, 0.f};

#define QLD(ic, ks)  (*(const f16x8*)(qb + ((size_t)((ic) * 4 + iw) * 2 + (ks)) * 512))
#define ULD(ct, ic, is) (*(const f16x8*)(ub + ((size_t)(CT0 + (ct)) * NIC + (ic) * 2 + (is)) * 512))

#define STAGE1(q0, q1, buf) do {                                              \
    f32x4 e0 = (f32x4){0.f, 0.f, 0.f, 0.f};                                   \
    f32x4 e1 = (f32x4){0.f, 0.f, 0.f, 0.f};                                   \
    e0 = __builtin_amdgcn_mfma_f32_16x16x32_f16(q0, kf[0][0], e0, 0, 0, 0);   \
    e0 = __builtin_amdgcn_mfma_f32_16x16x32_f16(q1, kf[0][1], e0, 0, 0, 0);   \
    e1 = __builtin_amdgcn_mfma_f32_16x16x32_f16(q0, kf[1][0], e1, 0, 0, 0);   \
    e1 = __builtin_amdgcn_mfma_f32_16x16x32_f16(q1, kf[1][1], e1, 0, 0, 0);   \
    f16x4 h0 = { (f16)__expf(e0[0]), (f16)__expf(e0[1]),                      \
                 (f16)__expf(e0[2]), (f16)__expf(e0[3]) };                    \
    f16x4 h1 = { (f16)__expf(e1[0]), (f16)__expf(e1[1]),                      \
                 (f16)__expf(e1[2]), (f16)__expf(e1[3]) };                    \
    *(f16x4*)&es[buf][et0][woff] = h0;                                        \
    *(f16x4*)&es[buf][et1][woff] = h1;                                        \
} while (0)

#define STAGE2(buf, u00, u01, u10, u11) do {                                  \
    _Pragma("unroll")                                                         \
    for (int jt = 0; jt < 4; ++jt) {                                          \
        f16x8 bf0 = *(const f16x8*)&es[buf][jt * 2 + 0][ln8];                 \
        acc[0][jt] = __builtin_amdgcn_mfma_f32_16x16x32_f16(u00, bf0, acc[0][jt], 0, 0, 0); \
        acc[1][jt] = __builtin_amdgcn_mfma_f32_16x16x32_f16(u10, bf0, acc[1][jt], 0, 0, 0); \
        f16x8 bf1 = *(const f16x8*)&es[buf][jt * 2 + 1][ln8];                 \
        acc[0][jt] = __builtin_amdgcn_mfma_f32_16x16x32_f16(u01, bf1, acc[0][jt], 0, 0, 0); \
        acc[1][jt] = __builtin_amdgcn_mfma_f32_16x16x32_f16(u11, bf1, acc[1][jt], 0, 0, 0); \
    }                                                                         \
} while (0)

#define BAR() do {                                                            \
    asm volatile("s_waitcnt lgkmcnt(0)" ::: "memory");                        \
    __builtin_amdgcn_s_barrier();                                             \
} while (0)

    // ---- prologue: E(0) -> es[0]; prefetch U(0), Q(1)
    f16x8 qA0 = QLD(0, 0), qA1 = QLD(0, 1);
    f16x8 uA0 = ULD(0, 0, 0), uA1 = ULD(0, 0, 1);
    f16x8 uA2 = ULD(1, 0, 0), uA3 = ULD(1, 0, 1);
    f16x8 qB0 = QLD(1, 0), qB1 = QLD(1, 1);
    STAGE1(qA0, qA1, 0);
    BAR();

    f16x8 uB0, uB1, uB2, uB3;
    for (int ic = 0; ic < NCH; ic += 2) {
        const int i1 = ic + 1;
        const int i2 = (ic + 2 < NCH) ? ic + 2 : NCH - 1;
        const int i3 = (ic + 3 < NCH) ? ic + 3 : NCH - 1;
        // ---- even half: stage2(ic) on es[0]/uA; stage1 E(ic+1)->es[1]
        uB0 = ULD(0, i1, 0); uB1 = ULD(0, i1, 1);
        uB2 = ULD(1, i1, 0); uB3 = ULD(1, i1, 1);
        qA0 = QLD(i2, 0); qA1 = QLD(i2, 1);       // for E(ic+2)
        STAGE2(0, uA0, uA1, uA2, uA3);
        STAGE1(qB0, qB1, 1);
        BAR();
        // ---- odd half: stage2(ic+1) on es[1]/uB; stage1 E(ic+2)->es[0]
        uA0 = ULD(0, i2, 0); uA1 = ULD(0, i2, 1);
        uA2 = ULD(1, i2, 0); uA3 = ULD(1, i2, 1);
        qB0 = QLD(i3, 0); qB1 = QLD(i3, 1);       // for E(ic+3)
        STAGE2(1, uB0, uB1, uB2, uB3);
        if (ic + 2 < NCH) STAGE1(qA0, qA1, 0);
        BAR();
    }

#undef QLD
#undef ULD
#undef STAGE1
#undef STAGE2
#undef BAR

    #pragma unroll
    for (int mt = 0; mt < 2; ++mt) {
        int cb = 32 * w + 16 * mt + quad * 4;
        #pragma unroll
        for (int jt = 0; jt < 4; ++jt) {
            int j = j0 + 16 * jt + l16;
            f16x4 h2 = { (f16)acc[mt][jt][0], (f16)acc[mt][jt][1],
                         (f16)acc[mt][jt][2], (f16)acc[mt][jt][3] };
            *(f16x4*)&o1T[((size_t)b * NPIX + j) * CIN + cb] = h2;
        }
    }
}

// ---------------------------------------------------------------------------
// Gamma conv via MFMA: out[b,o,j] = sum_c Wg[o,c]*o1[c,j] + gb[o], fp32 out.
// Tile 128(o) x 64(j), BK=32. grid (N/64, C/128, B), block 256.
// ---------------------------------------------------------------------------
__global__ __launch_bounds__(256) void gamma_conv_mfma(
    const f16* __restrict__ o1T, const f16* __restrict__ Wg,
    const float* __restrict__ gbias, float* __restrict__ out)
{
    __shared__ __align__(16) f16 As[128 * 40];
    __shared__ __align__(16) f16 Bs[64 * 40];
    const int t = threadIdx.x, w = t >> 6, lane = t & 63;
    const int quad = lane >> 4, l16 = lane & 15;
    const int wm = w & 1, wn = w >> 1;
    const int j0 = blockIdx.x * 64, o0 = blockIdx.y * 128, b = blockIdx.z;
    const int sub = t >> 2, le = t & 3;
    const f16* srcA = Wg + (size_t)(o0 + sub) * CIN + le * 8;
    const f16* srcB = o1T + ((size_t)b * NPIX + j0 + sub) * CIN + le * 8;
    const int ldsw = sub * 40 + le * 8;

    f32x4 acc[4][2];
    #pragma unroll
    for (int mt = 0; mt < 4; ++mt)
        #pragma unroll
        for (int nt = 0; nt < 2; ++nt)
            acc[mt][nt] = (f32x4){0.f, 0.f, 0.f, 0.f};

    for (int kk = 0; kk < CIN; kk += 32) {
        f16x8 ta0 = *(const f16x8*)(srcA + kk);
        f16x8 ta1 = *(const f16x8*)(srcA + (size_t)64 * CIN + kk);
        f16x8 tb0 = *(const f16x8*)(srcB + kk);
        __syncthreads();
        *(f16x8*)&As[ldsw]           = ta0;
        *(f16x8*)&As[64 * 40 + ldsw] = ta1;
        *(f16x8*)&Bs[ldsw]           = tb0;
        __syncthreads();
        f16x8 af[4], bf[2];
        #pragma unroll
        for (int mt = 0; mt < 4; ++mt)
            af[mt] = *(const f16x8*)&As[(64 * wm + 16 * mt + l16) * 40 + quad * 8];
        #pragma unroll
        for (int nt = 0; nt < 2; ++nt)
            bf[nt] = *(const f16x8*)&Bs[(32 * wn + 16 * nt + l16) * 40 + quad * 8];
        #pragma unroll
        for (int mt = 0; mt < 4; ++mt)
            #pragma unroll
            for (int nt = 0; nt < 2; ++nt)
                acc[mt][nt] = __builtin_amdgcn_mfma_f32_16x16x32_f16(
                    af[mt], bf[nt], acc[mt][nt], 0, 0, 0);
    }

    #pragma unroll
    for (int mt = 0; mt < 4; ++mt)
        #pragma unroll
        for (int r = 0; r < 4; ++r) {
            int o = o0 + 64 * wm + 16 * mt + quad * 4 + r;
            float bv = gbias[o];
            #pragma unroll
            for (int nt = 0; nt < 2; ++nt) {
                int j = j0 + 32 * wn + 16 * nt + l16;
                out[((size_t)b * CIN + o) * NPIX + j] = acc[mt][nt][r] + bv;
            }
        }
}

// ---------------------------------------------------------------------------
extern "C" void kernel_launch(void* const* d_in, const int* in_sizes, int n_in,
                              void* d_out, int out_size, void* d_ws, size_t ws_size,
                              hipStream_t stream) {
    const float* x   = (const float*)d_in[0];
    const float* qw  = (const float*)d_in[1];
    const float* qbv = (const float*)d_in[2];
    const float* kw  = (const float*)d_in[3];
    const float* kbv = (const float*)d_in[4];
    const float* vw  = (const float*)d_in[5];
    const float* vbv = (const float*)d_in[6];
    const float* gw  = (const float*)d_in[7];
    const float* gbv = (const float*)d_in[8];
    float* out = (float*)d_out;

    const size_t BCN  = (size_t)BATCH * CIN * NPIX;   // 4,718,592
    const size_t BN   = (size_t)BATCH * NPIX;         // 18,432
    const size_t BNCK = (size_t)BATCH * NPIX * CKD;   // 1,179,648

    // ws layout (~36 MB)
    f16* q_blk = (f16*)d_ws;          // 2.36 MB
    f16* k_blk = q_blk + BNCK;        // 2.36 MB
    f16* u_blk = k_blk + BNCK;        // 9.44 MB
    f16* xT    = u_blk + BCN;         // 9.44 MB
    f16* o1T   = xT + BCN;            // 9.44 MB
    f16* Wqk   = o1T + BCN;
    f16* Wv    = Wqk + 128 * 256;
    f16* Wg    = Wv + 256 * 256;
    float* S   = (float*)(Wg + 256 * 256);   // 0.07 MB
    float* Pred= S + BN;                      // 2.65 MB

    cast_w<<<160, 256, 0, stream>>>(qw, kw, vw, gw, Wqk, Wv, Wg);
    cast_xT<<<dim3(NPIX / 64, CIN / 64, BATCH), 256, 0, stream>>>(x, xT);
    qk_conv_mfma<<<dim3(NPIX / 32, BATCH), 256, 0, stream>>>(xT, Wqk, qbv, kbv, q_blk, k_blk);
    energy_S<<<dim3(NPIX / 64, NPIX / 128, BATCH), 256, 0, stream>>>(q_blk, k_blk, Pred);
    reduce_S<<<(int)(BN / 256), 256, 0, stream>>>(Pred, S);
    v_conv_mfma<<<dim3(NPIX / 64, CIN / 128, BATCH), 256, 0, stream>>>(xT, Wv, vbv, S, u_blk);
    fused_bmm<<<NJB * BATCH, 512, 0, stream>>>(q_blk, k_blk, u_blk, o1T);
    gamma_conv_mfma<<<dim3(NPIX / 64, CIN / 128, BATCH), 256, 0, stream>>>(o1T, Wg, gbv, out);
}